// Round 12
// baseline (135.958 us; speedup 1.0000x reference)
//
#include <hip/hip_runtime.h>
#include <hip/hip_bf16.h>

typedef __hip_bfloat16 HBF;
typedef __bf16 bf16x8 __attribute__((ext_vector_type(8)));
typedef __bf16 bf16x4 __attribute__((ext_vector_type(4)));
typedef float f32x4 __attribute__((ext_vector_type(4)));
typedef float float4v __attribute__((ext_vector_type(4)));

__device__ __forceinline__ float toF(float x) { return x; }
__device__ __forceinline__ float toF(HBF x) { return __bfloat162float(x); }

#define MFMA16(a, b, c) __builtin_amdgcn_mfma_f32_16x16x32_bf16((a), (b), (c), 0, 0, 0)
#define EXP2F(x) __builtin_amdgcn_exp2f(x)
#define QSCALE 0.18033688011112042f
#define MEMFENCE asm volatile("" ::: "memory")

// async global->LDS, 16B per lane. LDS dest must be wave-uniform base; HW adds lane*16.
__device__ __forceinline__ void gload_lds16(const HBF* g, HBF* l) {
  __builtin_amdgcn_global_load_lds((const __attribute__((address_space(1))) void*)g,
                                   (__attribute__((address_space(3))) void*)l, 16, 0, 0);
}

// ---------------- fused prep: x cast + W_qkv transpose + W_proj transpose ----------------
__global__ void prep_k(const float* __restrict__ x, HBF* __restrict__ xb,
                       const float* __restrict__ Wqkv, HBF* __restrict__ wqkv_t,
                       const float* __restrict__ Wproj, HBF* __restrict__ wproj_t) {
  const int bid = blockIdx.x, tid = threadIdx.x;
  if (bid < 4096) {
    int i = bid * 256 + tid;
    float4v a = reinterpret_cast<const float4v*>(x)[i];
    HBF o[4] = {__float2bfloat16(a.x), __float2bfloat16(a.y),
                __float2bfloat16(a.z), __float2bfloat16(a.w)};
    *reinterpret_cast<ulonglong1*>(&xb[i * 4]) = *reinterpret_cast<ulonglong1*>(o);
    return;
  }
  __shared__ float tile[32][33];
  const float* in;
  HBF* out;
  int R, C, gx, gy;
  size_t base;
  if (bid < 7168) {  // W_qkv (16,1024,192) -> (16,192,1024)
    int t = bid - 4096;
    int gz = t / 192, rem = t % 192;
    gy = rem / 6; gx = rem % 6;
    R = 1024; C = 192;
    base = (size_t)gz * R * C;
    in = Wqkv; out = wqkv_t;
  } else {           // W_proj (1024,1024) -> transposed
    int t = bid - 7168;
    gy = t / 32; gx = t % 32;
    R = 1024; C = 1024;
    base = 0;
    in = Wproj; out = wproj_t;
  }
  int r0 = gy * 32, c0 = gx * 32;
  int tx = tid & 31, ty = tid >> 5;
#pragma unroll
  for (int i = ty; i < 32; i += 8)
    tile[i][tx] = in[base + (size_t)(r0 + i) * C + c0 + tx];
  __syncthreads();
#pragma unroll
  for (int i = ty; i < 32; i += 8)
    out[base + (size_t)(c0 + i) * R + r0 + tx] = __float2bfloat16(tile[tx][i]);
}

// ---------------- QKV GEMM v2: 256x192x64 tiles -> 256 blocks (1/CU), 8-phase ----------------
__launch_bounds__(512, 1)
__global__ void gemm_qkv_8ph(const HBF* __restrict__ A, const HBF* __restrict__ Bt,
                             const float* __restrict__ bias,
                             HBF* __restrict__ Kout, HBF* __restrict__ Qout,
                             HBF* __restrict__ Vtout) {
  __shared__ __align__(16) HBF As[2][16384];
  __shared__ __align__(16) HBF Bs[2][12288];
  const int tid = threadIdx.x, lane = tid & 63, w = tid >> 6;
  const int lo = lane & 15, g4 = lane >> 4;
  const int wr = w >> 2, wc = w & 3;
  const int s = ((int)blockIdx.x & 7) * 32 + ((int)blockIdx.x >> 3);
  const int bx = s & 15, by = s >> 4;
  const int m0 = by * 256, n0 = bx * 192;  // bx == head
  const int NT = 16;  // K=1024 / 64

  f32x4 acc[8][3];
#pragma unroll
  for (int i = 0; i < 8; i++)
#pragma unroll
    for (int j = 0; j < 3; j++) acc[i][j] = (f32x4){0.f, 0.f, 0.f, 0.f};
  bf16x8 af[8][2], bfr[3][2];

  const int rl0 = w * 8 + (lane >> 3);
  const int rl1 = 64 + rl0;
  const int kc0 = (lane & 7) ^ (rl0 & 7);
  const int kc1 = (lane & 7) ^ (rl1 & 7);

  auto stageA = [&](int kt, int hf) {
    HBF* base = &As[kt & 1][hf * 8192];
    const int r0g = m0 + hf * 128;
    gload_lds16(A + (size_t)(r0g + rl0) * 1024 + kt * 64 + kc0 * 8, base + w * 512);
    gload_lds16(A + (size_t)(r0g + rl1) * 1024 + kt * 64 + kc1 * 8, base + 4096 + w * 512);
  };
  auto stageB = [&](int kt, int g) {
    gload_lds16(Bt + (size_t)(n0 + g * 64 + rl0) * 1024 + kt * 64 + kc0 * 8,
                &Bs[kt & 1][g * 4096] + w * 512);
  };
  auto ldA = [&](int bb, int mt, int ks) -> bf16x8 {
    int row = wr * 128 + mt * 16 + lo;
    return *reinterpret_cast<const bf16x8*>(&As[bb][row * 64 + ((ks * 32 + g4 * 8) ^ ((row & 7) * 8))]);
  };
  auto ldB = [&](int bb, int nt, int ks) -> bf16x8 {
    int row = wc * 48 + nt * 16 + lo;
    return *reinterpret_cast<const bf16x8*>(&Bs[bb][row * 64 + ((ks * 32 + g4 * 8) ^ ((row & 7) * 8))]);
  };

  stageA(0, 0); stageA(0, 1); stageB(0, 0); stageB(0, 1); stageB(0, 2);
  stageA(1, 0); stageA(1, 1);
  asm volatile("s_waitcnt vmcnt(4)" ::: "memory");
  __builtin_amdgcn_s_barrier();
  MEMFENCE;

  for (int t = 0; t < NT; ++t) {
    const int bb = t & 1;
#pragma unroll
    for (int mt = 0; mt < 4; ++mt) { af[mt][0] = ldA(bb, mt, 0); af[mt][1] = ldA(bb, mt, 1); }
#pragma unroll
    for (int nt = 0; nt < 2; ++nt) { bfr[nt][0] = ldB(bb, nt, 0); bfr[nt][1] = ldB(bb, nt, 1); }
    if (t + 1 < NT) stageB(t + 1, 0);
    MEMFENCE; __builtin_amdgcn_s_barrier(); MEMFENCE;
    __builtin_amdgcn_s_setprio(1);
#pragma unroll
    for (int mt = 0; mt < 4; ++mt)
#pragma unroll
      for (int nt = 0; nt < 2; ++nt)
#pragma unroll
        for (int ks = 0; ks < 2; ++ks) acc[mt][nt] = MFMA16(af[mt][ks], bfr[nt][ks], acc[mt][nt]);
    __builtin_amdgcn_s_setprio(0);
    MEMFENCE; __builtin_amdgcn_s_barrier(); MEMFENCE;
#pragma unroll
    for (int mt = 4; mt < 8; ++mt) { af[mt][0] = ldA(bb, mt, 0); af[mt][1] = ldA(bb, mt, 1); }
    if (t + 1 < NT) { stageB(t + 1, 1); stageB(t + 1, 2); }
    MEMFENCE; __builtin_amdgcn_s_barrier(); MEMFENCE;
    __builtin_amdgcn_s_setprio(1);
#pragma unroll
    for (int mt = 4; mt < 8; ++mt)
#pragma unroll
      for (int nt = 0; nt < 2; ++nt)
#pragma unroll
        for (int ks = 0; ks < 2; ++ks) acc[mt][nt] = MFMA16(af[mt][ks], bfr[nt][ks], acc[mt][nt]);
    __builtin_amdgcn_s_setprio(0);
    MEMFENCE; __builtin_amdgcn_s_barrier(); MEMFENCE;
    bfr[2][0] = ldB(bb, 2, 0); bfr[2][1] = ldB(bb, 2, 1);
    if (t + 2 < NT) stageA(t + 2, 0);
    MEMFENCE; __builtin_amdgcn_s_barrier(); MEMFENCE;
    __builtin_amdgcn_s_setprio(1);
#pragma unroll
    for (int mt = 0; mt < 4; ++mt)
#pragma unroll
      for (int ks = 0; ks < 2; ++ks) acc[mt][2] = MFMA16(af[mt][ks], bfr[2][ks], acc[mt][2]);
    __builtin_amdgcn_s_setprio(0);
    MEMFENCE; __builtin_amdgcn_s_barrier(); MEMFENCE;
    if (t + 2 < NT) stageA(t + 2, 1);
    MEMFENCE; __builtin_amdgcn_s_barrier(); MEMFENCE;
    __builtin_amdgcn_s_setprio(1);
#pragma unroll
    for (int mt = 4; mt < 8; ++mt)
#pragma unroll
      for (int ks = 0; ks < 2; ++ks) acc[mt][2] = MFMA16(af[mt][ks], bfr[2][ks], acc[mt][2]);
    __builtin_amdgcn_s_setprio(0);
    asm volatile("s_waitcnt vmcnt(4)" ::: "memory");
    __builtin_amdgcn_s_barrier();
    MEMFENCE;
  }

#pragma unroll
  for (int mt = 0; mt < 8; ++mt) {
    int mrow = m0 + wr * 128 + mt * 16 + g4 * 4;
#pragma unroll
    for (int nt = 0; nt < 3; ++nt) {
      int e = wc * 48 + nt * 16 + lo;
      float bv = bias[bx * 192 + e];
#pragma unroll
      for (int r = 0; r < 4; ++r) {
        int mm = mrow + r;
        int b = mm >> 11, n = mm & 2047;
        float v = acc[mt][nt][r] + bv;
        size_t bh64 = (size_t)(b * 16 + bx);
        if (e < 64)       Kout[(bh64 * 2048 + n) * 64 + e] = __float2bfloat16(v);
        else if (e < 128) Qout[(bh64 * 2048 + n) * 64 + e - 64] = __float2bfloat16(v * QSCALE);
        else              Vtout[(bh64 * 64 + (e - 128)) * 2048 + n] = __float2bfloat16(v);
      }
    }
  }
}

// ---------------- proj GEMM: m97-style 128x128x64, fp32 out + bias ----------------
__launch_bounds__(256)
__global__ void gemm_proj_k(const HBF* __restrict__ A, const HBF* __restrict__ Bt,
                            int M, int N, int K, const float* __restrict__ bias,
                            float* __restrict__ Cout) {
  __shared__ __align__(16) HBF As[128 * 64];
  __shared__ __align__(16) HBF Bs[128 * 64];
  const int tid = threadIdx.x;
  const int lane = tid & 63;
  const int w = tid >> 6;
  const int lo = lane & 15, g4 = lane >> 4;
  const int m0 = blockIdx.y * 128, n0 = blockIdx.x * 128;
  const int wr = w >> 1, wc = w & 1;

  const f32x4 zero = {0.f, 0.f, 0.f, 0.f};
  f32x4 acc[4][4];
#pragma unroll
  for (int i = 0; i < 4; i++)
#pragma unroll
    for (int j = 0; j < 4; j++) acc[i][j] = zero;

  for (int k0 = 0; k0 < K; k0 += 64) {
#pragma unroll
    for (int c = 0; c < 4; ++c) {
      int chunk = c * 256 + tid;
      int row = chunk >> 3, kc = (chunk & 7) * 8;
      HBF* ldsA = As + (size_t)(c * 256 + w * 64) * 8;
      HBF* ldsB = Bs + (size_t)(c * 256 + w * 64) * 8;
      gload_lds16(A + (size_t)(m0 + row) * K + k0 + kc, ldsA);
      gload_lds16(Bt + (size_t)(n0 + row) * K + k0 + kc, ldsB);
    }
    __syncthreads();
#pragma unroll
    for (int kk = 0; kk < 2; ++kk) {
      bf16x8 af[4], bfr[4];
#pragma unroll
      for (int i = 0; i < 4; i++)
        af[i] = *reinterpret_cast<const bf16x8*>(As + (size_t)(wr * 64 + i * 16 + lo) * 64 + kk * 32 + g4 * 8);
#pragma unroll
      for (int j = 0; j < 4; j++)
        bfr[j] = *reinterpret_cast<const bf16x8*>(Bs + (size_t)(wc * 64 + j * 16 + lo) * 64 + kk * 32 + g4 * 8);
#pragma unroll
      for (int i = 0; i < 4; i++)
#pragma unroll
        for (int j = 0; j < 4; j++) acc[i][j] = MFMA16(af[i], bfr[j], acc[i][j]);
    }
    __syncthreads();
  }

#pragma unroll
  for (int i = 0; i < 4; i++) {
    int mrow = m0 + wr * 64 + i * 16 + g4 * 4;
#pragma unroll
    for (int j = 0; j < 4; j++) {
      int col = n0 + wc * 64 + j * 16 + lo;
      float bv = bias[col];
#pragma unroll
      for (int r = 0; r < 4; r++)
        Cout[(size_t)(mrow + r) * N + col] = acc[i][j][r] + bv;
    }
  }
}

// ---------------- causal flash attention v8: diagonal-paired 32-row tiles, uniform cost ----------------
// grid 1024, 256 thr = 4 waves. xcd = lin&7, c = lin>>3, bh = xcd*4 + (c>>5), i = c&31.
// Block owns 32-row tiles jA = i (rows i*32..) and jB = 63-i. Wave w: 16 rows of A at
// i*32 + (w&1)*16 and 16 rows of B at (63-i)*32 + (w>>1)*16. Per kv-iter: tile B always,
// tile A while t < nkvA -> work-weighted cost = nkvA + nkvB = 33 units for EVERY block ->
// full 16-wave/CU residency with zero tail. K/V staged once, shared by both tiles.
// pLds (8KB) reused sequentially B-then-A (wave-local in-order DS). LDS = 40960 B.
__launch_bounds__(256, 4)
__global__ void attn_fwd_k(const HBF* __restrict__ Qb, const HBF* __restrict__ Kb,
                           const HBF* __restrict__ Vt, HBF* __restrict__ Ob) {
  __shared__ __align__(16) HBF Ks[2][64 * 64];
  __shared__ __align__(16) HBF Vs[2][64 * 64];
  __shared__ __align__(16) HBF pLds[4][16 * 64];
  const int tid = threadIdx.x;
  const int lane = tid & 63;
  const int w = tid >> 6;
  const int lo = lane & 15, g4 = lane >> 4;

  const int lin = blockIdx.x;
  const int xcd = lin & 7, c = lin >> 3;
  const int bh = xcd * 4 + (c >> 5);
  const int i = c & 31;
  const int b = bh >> 4, h = bh & 15;
  const int qA16 = i * 32 + (w & 1) * 16;           // tile A 16-row base for this wave
  const int qB16 = (63 - i) * 32 + (w >> 1) * 16;   // tile B 16-row base
  const int nkvA = i / 2 + 1;
  const int nkvB = (63 - i) / 2 + 1;

  const HBF* Qp = Qb + (size_t)bh * 2048 * 64;
  const HBF* Kp = Kb + (size_t)bh * 2048 * 64;
  const HBF* Vp = Vt + (size_t)bh * 64 * 2048;

  bf16x8 qfA[2], qfB[2];
#pragma unroll
  for (int ds = 0; ds < 2; ds++) {
    qfA[ds] = *reinterpret_cast<const bf16x8*>(Qp + (size_t)(qA16 + lo) * 64 + ds * 32 + g4 * 8);
    qfB[ds] = *reinterpret_cast<const bf16x8*>(Qp + (size_t)(qB16 + lo) * 64 + ds * 32 + g4 * 8);
  }

  const f32x4 zero = {0.f, 0.f, 0.f, 0.f};
  f32x4 oA[4], oB[4];
  float mA = -1e30f, lA = 0.f, mB = -1e30f, lB = 0.f;
#pragma unroll
  for (int j4 = 0; j4 < 4; j4++) { oA[j4] = zero; oB[j4] = zero; }

  const int srow = (lane >> 3) & 7;
  const int sch = lane & 7;
  const int psw = (lo & 7) << 4;  // pLds XOR key (bytes)

  auto stage = [&](int kv0, int sb) {
#pragma unroll
    for (int cc = 0; cc < 2; cc++) {
      int seg = w * 2 + cc;
      int row = seg * 8 + srow;
      gload_lds16(Kp + (size_t)(kv0 + row) * 64 + ((sch ^ (row & 7)) * 8), &Ks[sb][seg * 512]);
      gload_lds16(Vp + (size_t)row * 2048 + kv0 + ((sch ^ (row & 7)) * 8), &Vs[sb][seg * 512]);
    }
  };

  // full per-tile unit: QK^T -> online softmax -> P pack -> PV accumulate
  auto proc = [&](int kv0, int sb, const bf16x8 (&qf)[2], f32x4 (&o)[4],
                  float& m, float& l, int qb16, bool diag) {
    f32x4 st[4];
#pragma unroll
    for (int kt = 0; kt < 4; kt++) {
      int krow = kt * 16 + lo;
      bf16x8 kf0 = *reinterpret_cast<const bf16x8*>(&Ks[sb][krow * 64 + ((g4 ^ (krow & 7)) * 8)]);
      bf16x8 kf1 = *reinterpret_cast<const bf16x8*>(&Ks[sb][krow * 64 + (((4 + g4) ^ (krow & 7)) * 8)]);
      f32x4 z = zero;
      z = MFMA16(kf0, qf[0], z);
      z = MFMA16(kf1, qf[1], z);
      st[kt] = z;
    }
    const int q = qb16 + lo;
    float pmax = -1e30f;
    if (diag) {
#pragma unroll
      for (int kt = 0; kt < 4; kt++)
#pragma unroll
        for (int r = 0; r < 4; r++) {
          int key = kv0 + kt * 16 + g4 * 4 + r;
          float v = (key <= q) ? st[kt][r] : -1e30f;
          st[kt][r] = v;
          pmax = fmaxf(pmax, v);
        }
    } else {
#pragma unroll
      for (int kt = 0; kt < 4; kt++)
#pragma unroll
        for (int r = 0; r < 4; r++) pmax = fmaxf(pmax, st[kt][r]);
    }
    pmax = fmaxf(pmax, __shfl_xor(pmax, 16));
    pmax = fmaxf(pmax, __shfl_xor(pmax, 32));
    if (__any(pmax > m + 11.5f)) {  // defer-max
      float mn = fmaxf(m, pmax);
      float al = EXP2F(m - mn);
      m = mn;
      l *= al;
      float alr[4];
#pragma unroll
      for (int r = 0; r < 4; r++) alr[r] = __shfl(al, g4 * 4 + r);
#pragma unroll
      for (int j4 = 0; j4 < 4; j4++)
#pragma unroll
        for (int r = 0; r < 4; r++) o[j4][r] *= alr[r];
    }
#pragma unroll
    for (int kt = 0; kt < 4; kt++)
#pragma unroll
      for (int r = 0; r < 4; r++) {
        float p = EXP2F(st[kt][r] - m);
        st[kt][r] = p;
        l += p;  // lane-partial; reduced in epilogue
      }
#pragma unroll
    for (int kt = 0; kt < 4; kt++) {
      bf16x4 pk;
#pragma unroll
      for (int r = 0; r < 4; r++) pk[r] = (__bf16)st[kt][r];
      *reinterpret_cast<bf16x4*>(&pLds[w][lo * 64 + (((kt * 32 + g4 * 8) ^ psw) >> 1)]) = pk;
    }
    asm volatile("s_waitcnt lgkmcnt(0)" ::: "memory");
    __builtin_amdgcn_sched_barrier(0);
    bf16x8 pa[2];
#pragma unroll
    for (int ks = 0; ks < 2; ks++)
      pa[ks] = *reinterpret_cast<const bf16x8*>(&pLds[w][lo * 64 + (((ks * 64 + g4 * 16) ^ psw) >> 1)]);
#pragma unroll
    for (int j4 = 0; j4 < 4; j4++) {
      int vrow = j4 * 16 + lo;
#pragma unroll
      for (int ks = 0; ks < 2; ks++) {
        bf16x8 vb = *reinterpret_cast<const bf16x8*>(&Vs[sb][vrow * 64 + (((ks * 4 + g4) ^ (vrow & 7)) * 8)]);
        o[j4] = MFMA16(pa[ks], vb, o[j4]);
      }
    }
  };

  stage(0, 0);
  __syncthreads();

  for (int t = 0; t < nkvB; ++t) {
    const int kv0 = t * 64;
    const int sb = t & 1;
    if (t + 1 < nkvB) stage(kv0 + 64, sb ^ 1);  // prefetch under compute
    proc(kv0, sb, qfB, oB, mB, lB, qB16, t == nkvB - 1);
    if (t < nkvA) proc(kv0, sb, qfA, oA, mA, lA, qA16, t == nkvA - 1);
    __syncthreads();  // drains prefetch + protects LDS reuse
  }

  // ---- epilogue: both tiles ----
  lB += __shfl_xor(lB, 16); lB += __shfl_xor(lB, 32);
  lA += __shfl_xor(lA, 16); lA += __shfl_xor(lA, 32);
  float liB = 1.f / lB, liA = 1.f / lA;
  float lrB[4], lrA[4];
#pragma unroll
  for (int r = 0; r < 4; r++) {
    lrB[r] = __shfl(liB, g4 * 4 + r);
    lrA[r] = __shfl(liA, g4 * 4 + r);
  }
#pragma unroll
  for (int j4 = 0; j4 < 4; j4++)
#pragma unroll
    for (int r = 0; r < 4; r++) {
      int qB = qB16 + g4 * 4 + r;
      Ob[(size_t)(b * 2048 + qB) * 1024 + h * 64 + j4 * 16 + lo] =
          __float2bfloat16(oB[j4][r] * lrB[r]);
      int qA = qA16 + g4 * 4 + r;
      Ob[(size_t)(b * 2048 + qA) * 1024 + h * 64 + j4 * 16 + lo] =
          __float2bfloat16(oA[j4][r] * lrA[r]);
    }
}

// ---------------- launch ----------------
extern "C" void kernel_launch(void* const* d_in, const int* in_sizes, int n_in,
                              void* d_out, int out_size, void* d_ws, size_t ws_size,
                              hipStream_t stream) {
  const float* x      = (const float*)d_in[0];
  const float* W_qkv  = (const float*)d_in[1];
  const float* b_qkv  = (const float*)d_in[2];
  const float* W_proj = (const float*)d_in[3];
  const float* b_proj = (const float*)d_in[4];
  float* out = (float*)d_out;

  const int B = 2, N = 2048, D = 1024, H = 16, DH = 64;
  const int M = B * N;  // 4096

  char* ws = (char*)d_ws;
  HBF* xb      = (HBF*)ws; ws += (size_t)M * D * 2;
  HBF* wqkv_t  = (HBF*)ws; ws += (size_t)H * 3 * DH * D * 2;
  HBF* wproj_t = (HBF*)ws; ws += (size_t)D * D * 2;
  HBF* Qb      = (HBF*)ws; ws += (size_t)B * H * N * DH * 2;
  HBF* Kb      = (HBF*)ws; ws += (size_t)B * H * N * DH * 2;
  HBF* Vt      = (HBF*)ws; ws += (size_t)B * H * DH * N * 2;
  HBF* Ob      = (HBF*)ws; ws += (size_t)M * D * 2;

  prep_k<<<8192, 256, 0, stream>>>(x, xb, W_qkv, wqkv_t, W_proj, wproj_t);
  gemm_qkv_8ph<<<256, 512, 0, stream>>>(xb, wqkv_t, b_qkv, Kb, Qb, Vt);
  attn_fwd_k<<<1024, 256, 0, stream>>>(Qb, Kb, Vt, Ob);
  gemm_proj_k<<<dim3(D / 128, M / 128), 256, 0, stream>>>(Ob, wproj_t, M, D, D, b_proj, out);
}

// Round 13
// 111.804 us; speedup vs baseline: 1.2160x; 1.2160x over previous
//
#include <hip/hip_runtime.h>
#include <hip/hip_bf16.h>

typedef __hip_bfloat16 HBF;
typedef __bf16 bf16x8 __attribute__((ext_vector_type(8)));
typedef __bf16 bf16x4 __attribute__((ext_vector_type(4)));
typedef float f32x4 __attribute__((ext_vector_type(4)));
typedef float float4v __attribute__((ext_vector_type(4)));

__device__ __forceinline__ float toF(float x) { return x; }
__device__ __forceinline__ float toF(HBF x) { return __bfloat162float(x); }

#define MFMA16(a, b, c) __builtin_amdgcn_mfma_f32_16x16x32_bf16((a), (b), (c), 0, 0, 0)
#define EXP2F(x) __builtin_amdgcn_exp2f(x)
#define QSCALE 0.18033688011112042f
#define MEMFENCE asm volatile("" ::: "memory")

// async global->LDS, 16B per lane. LDS dest must be wave-uniform base; HW adds lane*16.
__device__ __forceinline__ void gload_lds16(const HBF* g, HBF* l) {
  __builtin_amdgcn_global_load_lds((const __attribute__((address_space(1))) void*)g,
                                   (__attribute__((address_space(3))) void*)l, 16, 0, 0);
}

// ---------------- fused prep: x cast + W_qkv transpose + W_proj transpose ----------------
__global__ void prep_k(const float* __restrict__ x, HBF* __restrict__ xb,
                       const float* __restrict__ Wqkv, HBF* __restrict__ wqkv_t,
                       const float* __restrict__ Wproj, HBF* __restrict__ wproj_t) {
  const int bid = blockIdx.x, tid = threadIdx.x;
  if (bid < 4096) {
    int i = bid * 256 + tid;
    float4v a = reinterpret_cast<const float4v*>(x)[i];
    HBF o[4] = {__float2bfloat16(a.x), __float2bfloat16(a.y),
                __float2bfloat16(a.z), __float2bfloat16(a.w)};
    *reinterpret_cast<ulonglong1*>(&xb[i * 4]) = *reinterpret_cast<ulonglong1*>(o);
    return;
  }
  __shared__ float tile[32][33];
  const float* in;
  HBF* out;
  int R, C, gx, gy;
  size_t base;
  if (bid < 7168) {  // W_qkv (16,1024,192) -> (16,192,1024)
    int t = bid - 4096;
    int gz = t / 192, rem = t % 192;
    gy = rem / 6; gx = rem % 6;
    R = 1024; C = 192;
    base = (size_t)gz * R * C;
    in = Wqkv; out = wqkv_t;
  } else {           // W_proj (1024,1024) -> transposed
    int t = bid - 7168;
    gy = t / 32; gx = t % 32;
    R = 1024; C = 1024;
    base = 0;
    in = Wproj; out = wproj_t;
  }
  int r0 = gy * 32, c0 = gx * 32;
  int tx = tid & 31, ty = tid >> 5;
#pragma unroll
  for (int i = ty; i < 32; i += 8)
    tile[i][tx] = in[base + (size_t)(r0 + i) * C + c0 + tx];
  __syncthreads();
#pragma unroll
  for (int i = ty; i < 32; i += 8)
    out[base + (size_t)(c0 + i) * R + r0 + tx] = __float2bfloat16(tile[tx][i]);
}

// ---------------- QKV GEMM v2: 256x192x64 tiles -> 256 blocks (1/CU), 8-phase ----------------
__launch_bounds__(512, 1)
__global__ void gemm_qkv_8ph(const HBF* __restrict__ A, const HBF* __restrict__ Bt,
                             const float* __restrict__ bias,
                             HBF* __restrict__ Kout, HBF* __restrict__ Qout,
                             HBF* __restrict__ Vtout) {
  __shared__ __align__(16) HBF As[2][16384];
  __shared__ __align__(16) HBF Bs[2][12288];
  const int tid = threadIdx.x, lane = tid & 63, w = tid >> 6;
  const int lo = lane & 15, g4 = lane >> 4;
  const int wr = w >> 2, wc = w & 3;
  const int s = ((int)blockIdx.x & 7) * 32 + ((int)blockIdx.x >> 3);
  const int bx = s & 15, by = s >> 4;
  const int m0 = by * 256, n0 = bx * 192;  // bx == head
  const int NT = 16;  // K=1024 / 64

  f32x4 acc[8][3];
#pragma unroll
  for (int i = 0; i < 8; i++)
#pragma unroll
    for (int j = 0; j < 3; j++) acc[i][j] = (f32x4){0.f, 0.f, 0.f, 0.f};
  bf16x8 af[8][2], bfr[3][2];

  const int rl0 = w * 8 + (lane >> 3);
  const int rl1 = 64 + rl0;
  const int kc0 = (lane & 7) ^ (rl0 & 7);
  const int kc1 = (lane & 7) ^ (rl1 & 7);

  auto stageA = [&](int kt, int hf) {
    HBF* base = &As[kt & 1][hf * 8192];
    const int r0g = m0 + hf * 128;
    gload_lds16(A + (size_t)(r0g + rl0) * 1024 + kt * 64 + kc0 * 8, base + w * 512);
    gload_lds16(A + (size_t)(r0g + rl1) * 1024 + kt * 64 + kc1 * 8, base + 4096 + w * 512);
  };
  auto stageB = [&](int kt, int g) {
    gload_lds16(Bt + (size_t)(n0 + g * 64 + rl0) * 1024 + kt * 64 + kc0 * 8,
                &Bs[kt & 1][g * 4096] + w * 512);
  };
  auto ldA = [&](int bb, int mt, int ks) -> bf16x8 {
    int row = wr * 128 + mt * 16 + lo;
    return *reinterpret_cast<const bf16x8*>(&As[bb][row * 64 + ((ks * 32 + g4 * 8) ^ ((row & 7) * 8))]);
  };
  auto ldB = [&](int bb, int nt, int ks) -> bf16x8 {
    int row = wc * 48 + nt * 16 + lo;
    return *reinterpret_cast<const bf16x8*>(&Bs[bb][row * 64 + ((ks * 32 + g4 * 8) ^ ((row & 7) * 8))]);
  };

  stageA(0, 0); stageA(0, 1); stageB(0, 0); stageB(0, 1); stageB(0, 2);
  stageA(1, 0); stageA(1, 1);
  asm volatile("s_waitcnt vmcnt(4)" ::: "memory");
  __builtin_amdgcn_s_barrier();
  MEMFENCE;

  for (int t = 0; t < NT; ++t) {
    const int bb = t & 1;
#pragma unroll
    for (int mt = 0; mt < 4; ++mt) { af[mt][0] = ldA(bb, mt, 0); af[mt][1] = ldA(bb, mt, 1); }
#pragma unroll
    for (int nt = 0; nt < 2; ++nt) { bfr[nt][0] = ldB(bb, nt, 0); bfr[nt][1] = ldB(bb, nt, 1); }
    if (t + 1 < NT) stageB(t + 1, 0);
    MEMFENCE; __builtin_amdgcn_s_barrier(); MEMFENCE;
    __builtin_amdgcn_s_setprio(1);
#pragma unroll
    for (int mt = 0; mt < 4; ++mt)
#pragma unroll
      for (int nt = 0; nt < 2; ++nt)
#pragma unroll
        for (int ks = 0; ks < 2; ++ks) acc[mt][nt] = MFMA16(af[mt][ks], bfr[nt][ks], acc[mt][nt]);
    __builtin_amdgcn_s_setprio(0);
    MEMFENCE; __builtin_amdgcn_s_barrier(); MEMFENCE;
#pragma unroll
    for (int mt = 4; mt < 8; ++mt) { af[mt][0] = ldA(bb, mt, 0); af[mt][1] = ldA(bb, mt, 1); }
    if (t + 1 < NT) { stageB(t + 1, 1); stageB(t + 1, 2); }
    MEMFENCE; __builtin_amdgcn_s_barrier(); MEMFENCE;
    __builtin_amdgcn_s_setprio(1);
#pragma unroll
    for (int mt = 4; mt < 8; ++mt)
#pragma unroll
      for (int nt = 0; nt < 2; ++nt)
#pragma unroll
        for (int ks = 0; ks < 2; ++ks) acc[mt][nt] = MFMA16(af[mt][ks], bfr[nt][ks], acc[mt][nt]);
    __builtin_amdgcn_s_setprio(0);
    MEMFENCE; __builtin_amdgcn_s_barrier(); MEMFENCE;
    bfr[2][0] = ldB(bb, 2, 0); bfr[2][1] = ldB(bb, 2, 1);
    if (t + 2 < NT) stageA(t + 2, 0);
    MEMFENCE; __builtin_amdgcn_s_barrier(); MEMFENCE;
    __builtin_amdgcn_s_setprio(1);
#pragma unroll
    for (int mt = 0; mt < 4; ++mt)
#pragma unroll
      for (int ks = 0; ks < 2; ++ks) acc[mt][2] = MFMA16(af[mt][ks], bfr[2][ks], acc[mt][2]);
    __builtin_amdgcn_s_setprio(0);
    MEMFENCE; __builtin_amdgcn_s_barrier(); MEMFENCE;
    if (t + 2 < NT) stageA(t + 2, 1);
    MEMFENCE; __builtin_amdgcn_s_barrier(); MEMFENCE;
    __builtin_amdgcn_s_setprio(1);
#pragma unroll
    for (int mt = 4; mt < 8; ++mt)
#pragma unroll
      for (int ks = 0; ks < 2; ++ks) acc[mt][2] = MFMA16(af[mt][ks], bfr[2][ks], acc[mt][2]);
    __builtin_amdgcn_s_setprio(0);
    asm volatile("s_waitcnt vmcnt(4)" ::: "memory");
    __builtin_amdgcn_s_barrier();
    MEMFENCE;
  }

#pragma unroll
  for (int mt = 0; mt < 8; ++mt) {
    int mrow = m0 + wr * 128 + mt * 16 + g4 * 4;
#pragma unroll
    for (int nt = 0; nt < 3; ++nt) {
      int e = wc * 48 + nt * 16 + lo;
      float bv = bias[bx * 192 + e];
#pragma unroll
      for (int r = 0; r < 4; ++r) {
        int mm = mrow + r;
        int b = mm >> 11, n = mm & 2047;
        float v = acc[mt][nt][r] + bv;
        size_t bh64 = (size_t)(b * 16 + bx);
        if (e < 64)       Kout[(bh64 * 2048 + n) * 64 + e] = __float2bfloat16(v);
        else if (e < 128) Qout[(bh64 * 2048 + n) * 64 + e - 64] = __float2bfloat16(v * QSCALE);
        else              Vtout[(bh64 * 64 + (e - 128)) * 2048 + n] = __float2bfloat16(v);
      }
    }
  }
}

// ---------------- proj GEMM: m97-style 128x128x64, fp32 out + bias ----------------
__launch_bounds__(256)
__global__ void gemm_proj_k(const HBF* __restrict__ A, const HBF* __restrict__ Bt,
                            int M, int N, int K, const float* __restrict__ bias,
                            float* __restrict__ Cout) {
  __shared__ __align__(16) HBF As[128 * 64];
  __shared__ __align__(16) HBF Bs[128 * 64];
  const int tid = threadIdx.x;
  const int lane = tid & 63;
  const int w = tid >> 6;
  const int lo = lane & 15, g4 = lane >> 4;
  const int m0 = blockIdx.y * 128, n0 = blockIdx.x * 128;
  const int wr = w >> 1, wc = w & 1;

  const f32x4 zero = {0.f, 0.f, 0.f, 0.f};
  f32x4 acc[4][4];
#pragma unroll
  for (int i = 0; i < 4; i++)
#pragma unroll
    for (int j = 0; j < 4; j++) acc[i][j] = zero;

  for (int k0 = 0; k0 < K; k0 += 64) {
#pragma unroll
    for (int c = 0; c < 4; ++c) {
      int chunk = c * 256 + tid;
      int row = chunk >> 3, kc = (chunk & 7) * 8;
      HBF* ldsA = As + (size_t)(c * 256 + w * 64) * 8;
      HBF* ldsB = Bs + (size_t)(c * 256 + w * 64) * 8;
      gload_lds16(A + (size_t)(m0 + row) * K + k0 + kc, ldsA);
      gload_lds16(Bt + (size_t)(n0 + row) * K + k0 + kc, ldsB);
    }
    __syncthreads();
#pragma unroll
    for (int kk = 0; kk < 2; ++kk) {
      bf16x8 af[4], bfr[4];
#pragma unroll
      for (int i = 0; i < 4; i++)
        af[i] = *reinterpret_cast<const bf16x8*>(As + (size_t)(wr * 64 + i * 16 + lo) * 64 + kk * 32 + g4 * 8);
#pragma unroll
      for (int j = 0; j < 4; j++)
        bfr[j] = *reinterpret_cast<const bf16x8*>(Bs + (size_t)(wc * 64 + j * 16 + lo) * 64 + kk * 32 + g4 * 8);
#pragma unroll
      for (int i = 0; i < 4; i++)
#pragma unroll
        for (int j = 0; j < 4; j++) acc[i][j] = MFMA16(af[i], bfr[j], acc[i][j]);
    }
    __syncthreads();
  }

#pragma unroll
  for (int i = 0; i < 4; i++) {
    int mrow = m0 + wr * 64 + i * 16 + g4 * 4;
#pragma unroll
    for (int j = 0; j < 4; j++) {
      int col = n0 + wc * 64 + j * 16 + lo;
      float bv = bias[col];
#pragma unroll
      for (int r = 0; r < 4; r++)
        Cout[(size_t)(mrow + r) * N + col] = acc[i][j][r] + bv;
    }
  }
}

// ---------------- causal flash attention v9: v7 skeleton, KVBLK=128 ----------------
// grid 1024 flat, 256 thr = 4 waves, ONE 64-row q-tile per block (wave = 16 distinct rows).
// KVBLK=128 = 2 x 64-key sub-tiles, double-buffered (K/V 64KB) + pLds 16KB = 81920 B
// -> 2 blocks/CU resident, 512 blocks queued; dispatch order longest-first (j descending,
// bh spread over XCDs) -> hardware refill approximates LPT. Halves iteration count and
// barrier/stage events vs KVBLK=64. Swapped QK^T, exp2-domain softmax, defer-max,
// deferred l-reduce, swizzled pLds (byte ^= (q&7)<<4).
__launch_bounds__(256, 2)
__global__ void attn_fwd_k(const HBF* __restrict__ Qb, const HBF* __restrict__ Kb,
                           const HBF* __restrict__ Vt, HBF* __restrict__ Ob) {
  __shared__ __align__(16) HBF Ks[2][2][4096];  // [dbuf][sub][64key x 64d]
  __shared__ __align__(16) HBF Vs[2][2][4096];  // [dbuf][sub][64d x 64key]
  __shared__ __align__(16) HBF pLds[4][2048];   // wave-local 16 q x 128 key
  const int tid = threadIdx.x;
  const int lane = tid & 63;
  const int w = tid >> 6;
  const int lo = lane & 15, g4 = lane >> 4;

  const int lin = blockIdx.x;
  const int xcd = lin & 7, c = lin >> 3;       // c in 0..127
  const int bh = xcd * 4 + (c & 3);            // 4 (b,h) per XCD -> KV L2-clustered
  const int j = 31 - (c >> 2);                 // longest tiles dispatched first
  const int b = bh >> 4, h = bh & 15;
  const int qrow0 = j * 64 + w * 16;
  const int nkv = (j + 2) >> 1;                // 128-key iterations

  const HBF* Qp = Qb + (size_t)bh * 2048 * 64;
  const HBF* Kp = Kb + (size_t)bh * 2048 * 64;
  const HBF* Vp = Vt + (size_t)bh * 64 * 2048;

  bf16x8 qf[2];
#pragma unroll
  for (int ds = 0; ds < 2; ds++)
    qf[ds] = *reinterpret_cast<const bf16x8*>(Qp + (size_t)(qrow0 + lo) * 64 + ds * 32 + g4 * 8);

  const f32x4 zero = {0.f, 0.f, 0.f, 0.f};
  f32x4 o[4];
  float m = -1e30f, l = 0.f;
#pragma unroll
  for (int j4 = 0; j4 < 4; j4++) o[j4] = zero;

  const int srow = (lane >> 3) & 7;
  const int sch = lane & 7;
  const int psw = (lo & 7) << 4;  // pLds XOR key (bytes)

  auto stage = [&](int kv0, int sb) {  // kv0 = 128-aligned
#pragma unroll
    for (int sub = 0; sub < 2; sub++)
#pragma unroll
      for (int cc = 0; cc < 2; cc++) {
        int seg = w * 2 + cc;
        int row = seg * 8 + srow;
        gload_lds16(Kp + (size_t)(kv0 + sub * 64 + row) * 64 + ((sch ^ (row & 7)) * 8),
                    &Ks[sb][sub][seg * 512]);
        gload_lds16(Vp + (size_t)row * 2048 + kv0 + sub * 64 + ((sch ^ (row & 7)) * 8),
                    &Vs[sb][sub][seg * 512]);
      }
  };

  stage(0, 0);
  __syncthreads();

  for (int t = 0; t < nkv; ++t) {
    const int kv0 = t * 128;
    const int sb = t & 1;
    if (t + 1 < nkv) stage(kv0 + 128, sb ^ 1);  // prefetch under compute

    // ---- S^T = K · Q^T over 128 keys (2 subs x 4 kt) ----
    f32x4 st[2][4];
#pragma unroll
    for (int sub = 0; sub < 2; sub++)
#pragma unroll
      for (int kt = 0; kt < 4; kt++) {
        int krow = kt * 16 + lo;
        bf16x8 kf0 = *reinterpret_cast<const bf16x8*>(&Ks[sb][sub][krow * 64 + ((g4 ^ (krow & 7)) * 8)]);
        bf16x8 kf1 = *reinterpret_cast<const bf16x8*>(&Ks[sb][sub][krow * 64 + (((4 + g4) ^ (krow & 7)) * 8)]);
        f32x4 z = zero;
        z = MFMA16(kf0, qf[0], z);
        z = MFMA16(kf1, qf[1], z);
        st[sub][kt] = z;
      }

    // ---- online softmax (lane owns q-col = qrow0 + lo) ----
    const int q = qrow0 + lo;
    float pmax = -1e30f;
    if (t == nkv - 1) {  // diagonal iter: mask (covers fully-masked sub1 for even j)
#pragma unroll
      for (int sub = 0; sub < 2; sub++)
#pragma unroll
        for (int kt = 0; kt < 4; kt++)
#pragma unroll
          for (int r = 0; r < 4; r++) {
            int key = kv0 + sub * 64 + kt * 16 + g4 * 4 + r;
            float v = (key <= q) ? st[sub][kt][r] : -1e30f;
            st[sub][kt][r] = v;
            pmax = fmaxf(pmax, v);
          }
    } else {
#pragma unroll
      for (int sub = 0; sub < 2; sub++)
#pragma unroll
        for (int kt = 0; kt < 4; kt++)
#pragma unroll
          for (int r = 0; r < 4; r++) pmax = fmaxf(pmax, st[sub][kt][r]);
    }
    pmax = fmaxf(pmax, __shfl_xor(pmax, 16));
    pmax = fmaxf(pmax, __shfl_xor(pmax, 32));
    if (__any(pmax > m + 11.5f)) {  // defer-max
      float mn = fmaxf(m, pmax);
      float al = EXP2F(m - mn);
      m = mn;
      l *= al;
      float alr[4];
#pragma unroll
      for (int r = 0; r < 4; r++) alr[r] = __shfl(al, g4 * 4 + r);
#pragma unroll
      for (int j4 = 0; j4 < 4; j4++)
#pragma unroll
        for (int r = 0; r < 4; r++) o[j4][r] *= alr[r];
    }
#pragma unroll
    for (int sub = 0; sub < 2; sub++)
#pragma unroll
      for (int kt = 0; kt < 4; kt++)
#pragma unroll
        for (int r = 0; r < 4; r++) {
          float p = EXP2F(st[sub][kt][r] - m);
          st[sub][kt][r] = p;
          l += p;  // lane-partial; reduced in epilogue
        }
    // pack P -> swizzled pLds: row = q (lo), byte-in-row = key*2 ^ psw, row stride 256B
#pragma unroll
    for (int sub = 0; sub < 2; sub++)
#pragma unroll
      for (int kt = 0; kt < 4; kt++) {
        bf16x4 pk;
#pragma unroll
        for (int r = 0; r < 4; r++) pk[r] = (__bf16)st[sub][kt][r];
        *reinterpret_cast<bf16x4*>(
            &pLds[w][lo * 128 + (((sub * 128 + kt * 32 + g4 * 8) ^ psw) >> 1)]) = pk;
      }
    asm volatile("s_waitcnt lgkmcnt(0)" ::: "memory");
    __builtin_amdgcn_sched_barrier(0);

    // ---- PV: 4 ks-groups of 32 keys ----
    bf16x8 pa[4];
#pragma unroll
    for (int ks = 0; ks < 4; ks++)
      pa[ks] = *reinterpret_cast<const bf16x8*>(
          &pLds[w][lo * 128 + (((ks * 64 + g4 * 16) ^ psw) >> 1)]);
#pragma unroll
    for (int j4 = 0; j4 < 4; j4++) {
      int vrow = j4 * 16 + lo;
#pragma unroll
      for (int ks = 0; ks < 4; ks++) {
        bf16x8 vb = *reinterpret_cast<const bf16x8*>(
            &Vs[sb][ks >> 1][vrow * 64 + ((((ks & 1) * 4 + g4) ^ (vrow & 7)) * 8)]);
        o[j4] = MFMA16(pa[ks], vb, o[j4]);
      }
    }
    __syncthreads();  // drains prefetch (full compute phase elapsed) + protects LDS reuse
  }

  // ---- epilogue ----
  l += __shfl_xor(l, 16);
  l += __shfl_xor(l, 32);
  float linv = 1.f / l;
  float lr[4];
#pragma unroll
  for (int r = 0; r < 4; r++) lr[r] = __shfl(linv, g4 * 4 + r);
#pragma unroll
  for (int j4 = 0; j4 < 4; j4++)
#pragma unroll
    for (int r = 0; r < 4; r++) {
      int q = qrow0 + g4 * 4 + r;
      Ob[(size_t)(b * 2048 + q) * 1024 + h * 64 + j4 * 16 + lo] =
          __float2bfloat16(o[j4][r] * lr[r]);
    }
}

// ---------------- launch ----------------
extern "C" void kernel_launch(void* const* d_in, const int* in_sizes, int n_in,
                              void* d_out, int out_size, void* d_ws, size_t ws_size,
                              hipStream_t stream) {
  const float* x      = (const float*)d_in[0];
  const float* W_qkv  = (const float*)d_in[1];
  const float* b_qkv  = (const float*)d_in[2];
  const float* W_proj = (const float*)d_in[3];
  const float* b_proj = (const float*)d_in[4];
  float* out = (float*)d_out;

  const int B = 2, N = 2048, D = 1024, H = 16, DH = 64;
  const int M = B * N;  // 4096

  char* ws = (char*)d_ws;
  HBF* xb      = (HBF*)ws; ws += (size_t)M * D * 2;
  HBF* wqkv_t  = (HBF*)ws; ws += (size_t)H * 3 * DH * D * 2;
  HBF* wproj_t = (HBF*)ws; ws += (size_t)D * D * 2;
  HBF* Qb      = (HBF*)ws; ws += (size_t)B * H * N * DH * 2;
  HBF* Kb      = (HBF*)ws; ws += (size_t)B * H * N * DH * 2;
  HBF* Vt      = (HBF*)ws; ws += (size_t)B * H * DH * N * 2;
  HBF* Ob      = (HBF*)ws; ws += (size_t)M * D * 2;

  prep_k<<<8192, 256, 0, stream>>>(x, xb, W_qkv, wqkv_t, W_proj, wproj_t);
  gemm_qkv_8ph<<<256, 512, 0, stream>>>(xb, wqkv_t, b_qkv, Kb, Qb, Vt);
  attn_fwd_k<<<1024, 256, 0, stream>>>(Qb, Kb, Vt, Ob);
  gemm_proj_k<<<dim3(D / 128, M / 128), 256, 0, stream>>>(Ob, wproj_t, M, D, D, b_proj, out);
}

// Round 14
// 104.935 us; speedup vs baseline: 1.2956x; 1.0655x over previous
//
#include <hip/hip_runtime.h>
#include <hip/hip_bf16.h>

typedef __hip_bfloat16 HBF;
typedef __bf16 bf16x8 __attribute__((ext_vector_type(8)));
typedef __bf16 bf16x4 __attribute__((ext_vector_type(4)));
typedef float f32x4 __attribute__((ext_vector_type(4)));
typedef float float4v __attribute__((ext_vector_type(4)));

__device__ __forceinline__ float toF(float x) { return x; }
__device__ __forceinline__ float toF(HBF x) { return __bfloat162float(x); }

#define MFMA16(a, b, c) __builtin_amdgcn_mfma_f32_16x16x32_bf16((a), (b), (c), 0, 0, 0)
#define EXP2F(x) __builtin_amdgcn_exp2f(x)
#define QSCALE 0.18033688011112042f
#define MEMFENCE asm volatile("" ::: "memory")

// async global->LDS, 16B per lane. LDS dest must be wave-uniform base; HW adds lane*16.
__device__ __forceinline__ void gload_lds16(const HBF* g, HBF* l) {
  __builtin_amdgcn_global_load_lds((const __attribute__((address_space(1))) void*)g,
                                   (__attribute__((address_space(3))) void*)l, 16, 0, 0);
}

// ---------------- fused prep: x cast + W_qkv transpose + W_proj transpose ----------------
__global__ void prep_k(const float* __restrict__ x, HBF* __restrict__ xb,
                       const float* __restrict__ Wqkv, HBF* __restrict__ wqkv_t,
                       const float* __restrict__ Wproj, HBF* __restrict__ wproj_t) {
  const int bid = blockIdx.x, tid = threadIdx.x;
  if (bid < 4096) {
    int i = bid * 256 + tid;
    float4v a = reinterpret_cast<const float4v*>(x)[i];
    HBF o[4] = {__float2bfloat16(a.x), __float2bfloat16(a.y),
                __float2bfloat16(a.z), __float2bfloat16(a.w)};
    *reinterpret_cast<ulonglong1*>(&xb[i * 4]) = *reinterpret_cast<ulonglong1*>(o);
    return;
  }
  __shared__ float tile[32][33];
  const float* in;
  HBF* out;
  int R, C, gx, gy;
  size_t base;
  if (bid < 7168) {  // W_qkv (16,1024,192) -> (16,192,1024)
    int t = bid - 4096;
    int gz = t / 192, rem = t % 192;
    gy = rem / 6; gx = rem % 6;
    R = 1024; C = 192;
    base = (size_t)gz * R * C;
    in = Wqkv; out = wqkv_t;
  } else {           // W_proj (1024,1024) -> transposed
    int t = bid - 7168;
    gy = t / 32; gx = t % 32;
    R = 1024; C = 1024;
    base = 0;
    in = Wproj; out = wproj_t;
  }
  int r0 = gy * 32, c0 = gx * 32;
  int tx = tid & 31, ty = tid >> 5;
#pragma unroll
  for (int i = ty; i < 32; i += 8)
    tile[i][tx] = in[base + (size_t)(r0 + i) * C + c0 + tx];
  __syncthreads();
#pragma unroll
  for (int i = ty; i < 32; i += 8)
    out[base + (size_t)(c0 + i) * R + r0 + tx] = __float2bfloat16(tile[tx][i]);
}

// ---------------- QKV GEMM v3: 128x192x64 tiles -> 512 blocks (2/CU), counted vmcnt ----------------
// C[4096,3072] = xb * wqkv_t^T; BN=192 = one head -> h = bx. 8 waves (2M x 4N): wave C = 64x48.
// LDS 56KB (A 2x16KB, B 2x24KB) -> 2 blocks/CU = 4 waves/SIMD: second block hides barriers.
// Per tile: P0 {12 ds_read, stage B0(t+1), bar, 16 MFMA, bar}; P1 {2 ds_read, stage B1,B2(t+1)
// + A(t+2), bar, 8 MFMA, vmcnt(2) (tail: vmcnt(0)), bar}.
__launch_bounds__(512, 4)
__global__ void gemm_qkv_8ph(const HBF* __restrict__ A, const HBF* __restrict__ Bt,
                             const float* __restrict__ bias,
                             HBF* __restrict__ Kout, HBF* __restrict__ Qout,
                             HBF* __restrict__ Vtout) {
  __shared__ __align__(16) HBF As[2][8192];
  __shared__ __align__(16) HBF Bs[2][12288];
  const int tid = threadIdx.x, lane = tid & 63, w = tid >> 6;
  const int lo = lane & 15, g4 = lane >> 4;
  const int wr = w >> 2, wc = w & 3;
  // XCD-aware bijective swizzle: 512 = 8 * 64
  const int s = ((int)blockIdx.x & 7) * 64 + ((int)blockIdx.x >> 3);
  const int bx = s & 15, by = s >> 4;
  const int m0 = by * 128, n0 = bx * 192;  // bx == head
  const int NT = 16;  // K=1024 / 64

  f32x4 acc[4][3];
#pragma unroll
  for (int i = 0; i < 4; i++)
#pragma unroll
    for (int j = 0; j < 3; j++) acc[i][j] = (f32x4){0.f, 0.f, 0.f, 0.f};
  bf16x8 af[4][2], bfr[3][2];

  const int rl0 = w * 8 + (lane >> 3);       // 0..63
  const int rl1 = 64 + rl0;                  // 64..127
  const int kc0 = (lane & 7) ^ (rl0 & 7);    // pre-swizzled chunk
  const int kc1 = (lane & 7) ^ (rl1 & 7);

  // whole A tile (128 rows) of K-tile kt: 2 loads/thread
  auto stageA = [&](int kt) {
    HBF* base = &As[kt & 1][0];
    gload_lds16(A + (size_t)(m0 + rl0) * 1024 + kt * 64 + kc0 * 8, base + w * 512);
    gload_lds16(A + (size_t)(m0 + rl1) * 1024 + kt * 64 + kc1 * 8, base + 4096 + w * 512);
  };
  // B third g (64 rows) of K-tile kt: 1 load/thread
  auto stageB = [&](int kt, int g) {
    gload_lds16(Bt + (size_t)(n0 + g * 64 + rl0) * 1024 + kt * 64 + kc0 * 8,
                &Bs[kt & 1][g * 4096] + w * 512);
  };
  auto ldA = [&](int bb, int mt, int ks) -> bf16x8 {
    int row = wr * 64 + mt * 16 + lo;
    return *reinterpret_cast<const bf16x8*>(&As[bb][row * 64 + ((ks * 32 + g4 * 8) ^ ((row & 7) * 8))]);
  };
  auto ldB = [&](int bb, int nt, int ks) -> bf16x8 {
    int row = wc * 48 + nt * 16 + lo;
    return *reinterpret_cast<const bf16x8*>(&Bs[bb][row * 64 + ((ks * 32 + g4 * 8) ^ ((row & 7) * 8))]);
  };

  // prologue: tile0 (A 2 + B 3 = 5 loads) + tile1 A (2); vmcnt(2) -> tile0 complete
  stageA(0); stageB(0, 0); stageB(0, 1); stageB(0, 2);
  stageA(1);
  asm volatile("s_waitcnt vmcnt(2)" ::: "memory");
  __builtin_amdgcn_s_barrier();
  MEMFENCE;

  for (int t = 0; t < NT; ++t) {
    const int bb = t & 1;
    // ---- P0: read A mt0-3 + B nt0-1; stage B0(t+1); MFMA mt0-3 x nt0-1 ----
#pragma unroll
    for (int mt = 0; mt < 4; ++mt) { af[mt][0] = ldA(bb, mt, 0); af[mt][1] = ldA(bb, mt, 1); }
#pragma unroll
    for (int nt = 0; nt < 2; ++nt) { bfr[nt][0] = ldB(bb, nt, 0); bfr[nt][1] = ldB(bb, nt, 1); }
    if (t + 1 < NT) stageB(t + 1, 0);
    MEMFENCE; __builtin_amdgcn_s_barrier(); MEMFENCE;
    __builtin_amdgcn_s_setprio(1);
#pragma unroll
    for (int mt = 0; mt < 4; ++mt)
#pragma unroll
      for (int nt = 0; nt < 2; ++nt)
#pragma unroll
        for (int ks = 0; ks < 2; ++ks) acc[mt][nt] = MFMA16(af[mt][ks], bfr[nt][ks], acc[mt][nt]);
    __builtin_amdgcn_s_setprio(0);
    MEMFENCE; __builtin_amdgcn_s_barrier(); MEMFENCE;
    // ---- P1: read B nt2; stage B1,B2(t+1) + A(t+2); MFMA mt0-3 x nt2; counted wait ----
    bfr[2][0] = ldB(bb, 2, 0); bfr[2][1] = ldB(bb, 2, 1);
    if (t + 1 < NT) { stageB(t + 1, 1); stageB(t + 1, 2); }
    if (t + 2 < NT) stageA(t + 2);
    MEMFENCE; __builtin_amdgcn_s_barrier(); MEMFENCE;
    __builtin_amdgcn_s_setprio(1);
#pragma unroll
    for (int mt = 0; mt < 4; ++mt)
#pragma unroll
      for (int ks = 0; ks < 2; ++ks) acc[mt][2] = MFMA16(af[mt][ks], bfr[2][ks], acc[mt][2]);
    __builtin_amdgcn_s_setprio(0);
    if (t + 2 < NT) {
      asm volatile("s_waitcnt vmcnt(2)" ::: "memory");  // leave A(t+2) in flight
    } else {
      asm volatile("s_waitcnt vmcnt(0)" ::: "memory");  // tail: drain everything
    }
    __builtin_amdgcn_s_barrier();
    MEMFENCE;
  }

  // ---- scatter epilogue: h = bx, e = wc*48 + nt*16 + lo ----
#pragma unroll
  for (int mt = 0; mt < 4; ++mt) {
    int mrow = m0 + wr * 64 + mt * 16 + g4 * 4;
#pragma unroll
    for (int nt = 0; nt < 3; ++nt) {
      int e = wc * 48 + nt * 16 + lo;
      float bv = bias[bx * 192 + e];
#pragma unroll
      for (int r = 0; r < 4; ++r) {
        int mm = mrow + r;
        int b = mm >> 11, n = mm & 2047;
        float v = acc[mt][nt][r] + bv;
        size_t bh64 = (size_t)(b * 16 + bx);
        if (e < 64)       Kout[(bh64 * 2048 + n) * 64 + e] = __float2bfloat16(v);
        else if (e < 128) Qout[(bh64 * 2048 + n) * 64 + e - 64] = __float2bfloat16(v * QSCALE);
        else              Vtout[(bh64 * 64 + (e - 128)) * 2048 + n] = __float2bfloat16(v);
      }
    }
  }
}

// ---------------- proj GEMM: m97-style 128x128x64, fp32 out + bias ----------------
__launch_bounds__(256)
__global__ void gemm_proj_k(const HBF* __restrict__ A, const HBF* __restrict__ Bt,
                            int M, int N, int K, const float* __restrict__ bias,
                            float* __restrict__ Cout) {
  __shared__ __align__(16) HBF As[128 * 64];
  __shared__ __align__(16) HBF Bs[128 * 64];
  const int tid = threadIdx.x;
  const int lane = tid & 63;
  const int w = tid >> 6;
  const int lo = lane & 15, g4 = lane >> 4;
  const int m0 = blockIdx.y * 128, n0 = blockIdx.x * 128;
  const int wr = w >> 1, wc = w & 1;

  const f32x4 zero = {0.f, 0.f, 0.f, 0.f};
  f32x4 acc[4][4];
#pragma unroll
  for (int i = 0; i < 4; i++)
#pragma unroll
    for (int j = 0; j < 4; j++) acc[i][j] = zero;

  for (int k0 = 0; k0 < K; k0 += 64) {
#pragma unroll
    for (int c = 0; c < 4; ++c) {
      int chunk = c * 256 + tid;
      int row = chunk >> 3, kc = (chunk & 7) * 8;
      HBF* ldsA = As + (size_t)(c * 256 + w * 64) * 8;
      HBF* ldsB = Bs + (size_t)(c * 256 + w * 64) * 8;
      gload_lds16(A + (size_t)(m0 + row) * K + k0 + kc, ldsA);
      gload_lds16(Bt + (size_t)(n0 + row) * K + k0 + kc, ldsB);
    }
    __syncthreads();
#pragma unroll
    for (int kk = 0; kk < 2; ++kk) {
      bf16x8 af[4], bfr[4];
#pragma unroll
      for (int i = 0; i < 4; i++)
        af[i] = *reinterpret_cast<const bf16x8*>(As + (size_t)(wr * 64 + i * 16 + lo) * 64 + kk * 32 + g4 * 8);
#pragma unroll
      for (int j = 0; j < 4; j++)
        bfr[j] = *reinterpret_cast<const bf16x8*>(Bs + (size_t)(wc * 64 + j * 16 + lo) * 64 + kk * 32 + g4 * 8);
#pragma unroll
      for (int i = 0; i < 4; i++)
#pragma unroll
        for (int j = 0; j < 4; j++) acc[i][j] = MFMA16(af[i], bfr[j], acc[i][j]);
    }
    __syncthreads();
  }

#pragma unroll
  for (int i = 0; i < 4; i++) {
    int mrow = m0 + wr * 64 + i * 16 + g4 * 4;
#pragma unroll
    for (int j = 0; j < 4; j++) {
      int col = n0 + wc * 64 + j * 16 + lo;
      float bv = bias[col];
#pragma unroll
      for (int r = 0; r < 4; r++)
        Cout[(size_t)(mrow + r) * N + col] = acc[i][j][r] + bv;
    }
  }
}

// ---------------- causal flash attention v9: v7 skeleton, KVBLK=128 ----------------
__launch_bounds__(256, 2)
__global__ void attn_fwd_k(const HBF* __restrict__ Qb, const HBF* __restrict__ Kb,
                           const HBF* __restrict__ Vt, HBF* __restrict__ Ob) {
  __shared__ __align__(16) HBF Ks[2][2][4096];  // [dbuf][sub][64key x 64d]
  __shared__ __align__(16) HBF Vs[2][2][4096];  // [dbuf][sub][64d x 64key]
  __shared__ __align__(16) HBF pLds[4][2048];   // wave-local 16 q x 128 key
  const int tid = threadIdx.x;
  const int lane = tid & 63;
  const int w = tid >> 6;
  const int lo = lane & 15, g4 = lane >> 4;

  const int lin = blockIdx.x;
  const int xcd = lin & 7, c = lin >> 3;       // c in 0..127
  const int bh = xcd * 4 + (c & 3);            // 4 (b,h) per XCD -> KV L2-clustered
  const int j = 31 - (c >> 2);                 // longest tiles dispatched first
  const int b = bh >> 4, h = bh & 15;
  const int qrow0 = j * 64 + w * 16;
  const int nkv = (j + 2) >> 1;                // 128-key iterations

  const HBF* Qp = Qb + (size_t)bh * 2048 * 64;
  const HBF* Kp = Kb + (size_t)bh * 2048 * 64;
  const HBF* Vp = Vt + (size_t)bh * 64 * 2048;

  bf16x8 qf[2];
#pragma unroll
  for (int ds = 0; ds < 2; ds++)
    qf[ds] = *reinterpret_cast<const bf16x8*>(Qp + (size_t)(qrow0 + lo) * 64 + ds * 32 + g4 * 8);

  const f32x4 zero = {0.f, 0.f, 0.f, 0.f};
  f32x4 o[4];
  float m = -1e30f, l = 0.f;
#pragma unroll
  for (int j4 = 0; j4 < 4; j4++) o[j4] = zero;

  const int srow = (lane >> 3) & 7;
  const int sch = lane & 7;
  const int psw = (lo & 7) << 4;  // pLds XOR key (bytes)

  auto stage = [&](int kv0, int sb) {  // kv0 = 128-aligned
#pragma unroll
    for (int sub = 0; sub < 2; sub++)
#pragma unroll
      for (int cc = 0; cc < 2; cc++) {
        int seg = w * 2 + cc;
        int row = seg * 8 + srow;
        gload_lds16(Kp + (size_t)(kv0 + sub * 64 + row) * 64 + ((sch ^ (row & 7)) * 8),
                    &Ks[sb][sub][seg * 512]);
        gload_lds16(Vp + (size_t)row * 2048 + kv0 + sub * 64 + ((sch ^ (row & 7)) * 8),
                    &Vs[sb][sub][seg * 512]);
      }
  };

  stage(0, 0);
  __syncthreads();

  for (int t = 0; t < nkv; ++t) {
    const int kv0 = t * 128;
    const int sb = t & 1;
    if (t + 1 < nkv) stage(kv0 + 128, sb ^ 1);  // prefetch under compute

    // ---- S^T = K · Q^T over 128 keys (2 subs x 4 kt) ----
    f32x4 st[2][4];
#pragma unroll
    for (int sub = 0; sub < 2; sub++)
#pragma unroll
      for (int kt = 0; kt < 4; kt++) {
        int krow = kt * 16 + lo;
        bf16x8 kf0 = *reinterpret_cast<const bf16x8*>(&Ks[sb][sub][krow * 64 + ((g4 ^ (krow & 7)) * 8)]);
        bf16x8 kf1 = *reinterpret_cast<const bf16x8*>(&Ks[sb][sub][krow * 64 + (((4 + g4) ^ (krow & 7)) * 8)]);
        f32x4 z = zero;
        z = MFMA16(kf0, qf[0], z);
        z = MFMA16(kf1, qf[1], z);
        st[sub][kt] = z;
      }

    // ---- online softmax (lane owns q-col = qrow0 + lo) ----
    const int q = qrow0 + lo;
    float pmax = -1e30f;
    if (t == nkv - 1) {  // diagonal iter: mask (covers fully-masked sub1 for even j)
#pragma unroll
      for (int sub = 0; sub < 2; sub++)
#pragma unroll
        for (int kt = 0; kt < 4; kt++)
#pragma unroll
          for (int r = 0; r < 4; r++) {
            int key = kv0 + sub * 64 + kt * 16 + g4 * 4 + r;
            float v = (key <= q) ? st[sub][kt][r] : -1e30f;
            st[sub][kt][r] = v;
            pmax = fmaxf(pmax, v);
          }
    } else {
#pragma unroll
      for (int sub = 0; sub < 2; sub++)
#pragma unroll
        for (int kt = 0; kt < 4; kt++)
#pragma unroll
          for (int r = 0; r < 4; r++) pmax = fmaxf(pmax, st[sub][kt][r]);
    }
    pmax = fmaxf(pmax, __shfl_xor(pmax, 16));
    pmax = fmaxf(pmax, __shfl_xor(pmax, 32));
    if (__any(pmax > m + 11.5f)) {  // defer-max
      float mn = fmaxf(m, pmax);
      float al = EXP2F(m - mn);
      m = mn;
      l *= al;
      float alr[4];
#pragma unroll
      for (int r = 0; r < 4; r++) alr[r] = __shfl(al, g4 * 4 + r);
#pragma unroll
      for (int j4 = 0; j4 < 4; j4++)
#pragma unroll
        for (int r = 0; r < 4; r++) o[j4][r] *= alr[r];
    }
#pragma unroll
    for (int sub = 0; sub < 2; sub++)
#pragma unroll
      for (int kt = 0; kt < 4; kt++)
#pragma unroll
        for (int r = 0; r < 4; r++) {
          float p = EXP2F(st[sub][kt][r] - m);
          st[sub][kt][r] = p;
          l += p;  // lane-partial; reduced in epilogue
        }
    // pack P -> swizzled pLds: row = q (lo), byte-in-row = key*2 ^ psw, row stride 256B
#pragma unroll
    for (int sub = 0; sub < 2; sub++)
#pragma unroll
      for (int kt = 0; kt < 4; kt++) {
        bf16x4 pk;
#pragma unroll
        for (int r = 0; r < 4; r++) pk[r] = (__bf16)st[sub][kt][r];
        *reinterpret_cast<bf16x4*>(
            &pLds[w][lo * 128 + (((sub * 128 + kt * 32 + g4 * 8) ^ psw) >> 1)]) = pk;
      }
    asm volatile("s_waitcnt lgkmcnt(0)" ::: "memory");
    __builtin_amdgcn_sched_barrier(0);

    // ---- PV: 4 ks-groups of 32 keys ----
    bf16x8 pa[4];
#pragma unroll
    for (int ks = 0; ks < 4; ks++)
      pa[ks] = *reinterpret_cast<const bf16x8*>(
          &pLds[w][lo * 128 + (((ks * 64 + g4 * 16) ^ psw) >> 1)]);
#pragma unroll
    for (int j4 = 0; j4 < 4; j4++) {
      int vrow = j4 * 16 + lo;
#pragma unroll
      for (int ks = 0; ks < 4; ks++) {
        bf16x8 vb = *reinterpret_cast<const bf16x8*>(
            &Vs[sb][ks >> 1][vrow * 64 + ((((ks & 1) * 4 + g4) ^ (vrow & 7)) * 8)]);
        o[j4] = MFMA16(pa[ks], vb, o[j4]);
      }
    }
    __syncthreads();  // drains prefetch (full compute phase elapsed) + protects LDS reuse
  }

  // ---- epilogue ----
  l += __shfl_xor(l, 16);
  l += __shfl_xor(l, 32);
  float linv = 1.f / l;
  float lr[4];
#pragma unroll
  for (int r = 0; r < 4; r++) lr[r] = __shfl(linv, g4 * 4 + r);
#pragma unroll
  for (int j4 = 0; j4 < 4; j4++)
#pragma unroll
    for (int r = 0; r < 4; r++) {
      int q = qrow0 + g4 * 4 + r;
      Ob[(size_t)(b * 2048 + q) * 1024 + h * 64 + j4 * 16 + lo] =
          __float2bfloat16(o[j4][r] * lr[r]);
    }
}

// ---------------- launch ----------------
extern "C" void kernel_launch(void* const* d_in, const int* in_sizes, int n_in,
                              void* d_out, int out_size, void* d_ws, size_t ws_size,
                              hipStream_t stream) {
  const float* x      = (const float*)d_in[0];
  const float* W_qkv  = (const float*)d_in[1];
  const float* b_qkv  = (const float*)d_in[2];
  const float* W_proj = (const float*)d_in[3];
  const float* b_proj = (const float*)d_in[4];
  float* out = (float*)d_out;

  const int B = 2, N = 2048, D = 1024, H = 16, DH = 64;
  const int M = B * N;  // 4096

  char* ws = (char*)d_ws;
  HBF* xb      = (HBF*)ws; ws += (size_t)M * D * 2;
  HBF* wqkv_t  = (HBF*)ws; ws += (size_t)H * 3 * DH * D * 2;
  HBF* wproj_t = (HBF*)ws; ws += (size_t)D * D * 2;
  HBF* Qb      = (HBF*)ws; ws += (size_t)B * H * N * DH * 2;
  HBF* Kb      = (HBF*)ws; ws += (size_t)B * H * N * DH * 2;
  HBF* Vt      = (HBF*)ws; ws += (size_t)B * H * DH * N * 2;
  HBF* Ob      = (HBF*)ws; ws += (size_t)M * D * 2;

  prep_k<<<8192, 256, 0, stream>>>(x, xb, W_qkv, wqkv_t, W_proj, wproj_t);
  gemm_qkv_8ph<<<512, 512, 0, stream>>>(xb, wqkv_t, b_qkv, Kb, Qb, Vt);
  attn_fwd_k<<<1024, 256, 0, stream>>>(Qb, Kb, Vt, Ob);
  gemm_proj_k<<<dim3(D / 128, M / 128), 256, 0, stream>>>(Ob, wproj_t, M, D, D, b_proj, out);
}

// Round 15
// 97.227 us; speedup vs baseline: 1.3984x; 1.0793x over previous
//
#include <hip/hip_runtime.h>
#include <hip/hip_bf16.h>

typedef __hip_bfloat16 HBF;
typedef __bf16 bf16x8 __attribute__((ext_vector_type(8)));
typedef __bf16 bf16x4 __attribute__((ext_vector_type(4)));
typedef float f32x4 __attribute__((ext_vector_type(4)));
typedef float float4v __attribute__((ext_vector_type(4)));

__device__ __forceinline__ float toF(float x) { return x; }
__device__ __forceinline__ float toF(HBF x) { return __bfloat162float(x); }

#define MFMA16(a, b, c) __builtin_amdgcn_mfma_f32_16x16x32_bf16((a), (b), (c), 0, 0, 0)
#define EXP2F(x) __builtin_amdgcn_exp2f(x)
#define QSCALE 0.18033688011112042f
#define MEMFENCE asm volatile("" ::: "memory")

// async global->LDS, 16B per lane. LDS dest must be wave-uniform base; HW adds lane*16.
__device__ __forceinline__ void gload_lds16(const HBF* g, HBF* l) {
  __builtin_amdgcn_global_load_lds((const __attribute__((address_space(1))) void*)g,
                                   (__attribute__((address_space(3))) void*)l, 16, 0, 0);
}

// ---------------- fused prep: x cast + W_qkv transpose + W_proj transpose ----------------
__global__ void prep_k(const float* __restrict__ x, HBF* __restrict__ xb,
                       const float* __restrict__ Wqkv, HBF* __restrict__ wqkv_t,
                       const float* __restrict__ Wproj, HBF* __restrict__ wproj_t) {
  const int bid = blockIdx.x, tid = threadIdx.x;
  if (bid < 4096) {
    int i = bid * 256 + tid;
    float4v a = reinterpret_cast<const float4v*>(x)[i];
    HBF o[4] = {__float2bfloat16(a.x), __float2bfloat16(a.y),
                __float2bfloat16(a.z), __float2bfloat16(a.w)};
    *reinterpret_cast<ulonglong1*>(&xb[i * 4]) = *reinterpret_cast<ulonglong1*>(o);
    return;
  }
  __shared__ float tile[32][33];
  const float* in;
  HBF* out;
  int R, C, gx, gy;
  size_t base;
  if (bid < 7168) {  // W_qkv (16,1024,192) -> (16,192,1024)
    int t = bid - 4096;
    int gz = t / 192, rem = t % 192;
    gy = rem / 6; gx = rem % 6;
    R = 1024; C = 192;
    base = (size_t)gz * R * C;
    in = Wqkv; out = wqkv_t;
  } else {           // W_proj (1024,1024) -> transposed
    int t = bid - 7168;
    gy = t / 32; gx = t % 32;
    R = 1024; C = 1024;
    base = 0;
    in = Wproj; out = wproj_t;
  }
  int r0 = gy * 32, c0 = gx * 32;
  int tx = tid & 31, ty = tid >> 5;
#pragma unroll
  for (int i = ty; i < 32; i += 8)
    tile[i][tx] = in[base + (size_t)(r0 + i) * C + c0 + tx];
  __syncthreads();
#pragma unroll
  for (int i = ty; i < 32; i += 8)
    out[base + (size_t)(c0 + i) * R + r0 + tx] = __float2bfloat16(tile[tx][i]);
}

// ---------------- QKV GEMM v3: 128x192x64 tiles -> 512 blocks (2/CU), counted vmcnt ----------------
__launch_bounds__(512, 4)
__global__ void gemm_qkv_8ph(const HBF* __restrict__ A, const HBF* __restrict__ Bt,
                             const float* __restrict__ bias,
                             HBF* __restrict__ Kout, HBF* __restrict__ Qout,
                             HBF* __restrict__ Vtout) {
  __shared__ __align__(16) HBF As[2][8192];
  __shared__ __align__(16) HBF Bs[2][12288];
  const int tid = threadIdx.x, lane = tid & 63, w = tid >> 6;
  const int lo = lane & 15, g4 = lane >> 4;
  const int wr = w >> 2, wc = w & 3;
  const int s = ((int)blockIdx.x & 7) * 64 + ((int)blockIdx.x >> 3);
  const int bx = s & 15, by = s >> 4;
  const int m0 = by * 128, n0 = bx * 192;  // bx == head
  const int NT = 16;  // K=1024 / 64

  f32x4 acc[4][3];
#pragma unroll
  for (int i = 0; i < 4; i++)
#pragma unroll
    for (int j = 0; j < 3; j++) acc[i][j] = (f32x4){0.f, 0.f, 0.f, 0.f};
  bf16x8 af[4][2], bfr[3][2];

  const int rl0 = w * 8 + (lane >> 3);
  const int rl1 = 64 + rl0;
  const int kc0 = (lane & 7) ^ (rl0 & 7);
  const int kc1 = (lane & 7) ^ (rl1 & 7);

  auto stageA = [&](int kt) {
    HBF* base = &As[kt & 1][0];
    gload_lds16(A + (size_t)(m0 + rl0) * 1024 + kt * 64 + kc0 * 8, base + w * 512);
    gload_lds16(A + (size_t)(m0 + rl1) * 1024 + kt * 64 + kc1 * 8, base + 4096 + w * 512);
  };
  auto stageB = [&](int kt, int g) {
    gload_lds16(Bt + (size_t)(n0 + g * 64 + rl0) * 1024 + kt * 64 + kc0 * 8,
                &Bs[kt & 1][g * 4096] + w * 512);
  };
  auto ldA = [&](int bb, int mt, int ks) -> bf16x8 {
    int row = wr * 64 + mt * 16 + lo;
    return *reinterpret_cast<const bf16x8*>(&As[bb][row * 64 + ((ks * 32 + g4 * 8) ^ ((row & 7) * 8))]);
  };
  auto ldB = [&](int bb, int nt, int ks) -> bf16x8 {
    int row = wc * 48 + nt * 16 + lo;
    return *reinterpret_cast<const bf16x8*>(&Bs[bb][row * 64 + ((ks * 32 + g4 * 8) ^ ((row & 7) * 8))]);
  };

  stageA(0); stageB(0, 0); stageB(0, 1); stageB(0, 2);
  stageA(1);
  asm volatile("s_waitcnt vmcnt(2)" ::: "memory");
  __builtin_amdgcn_s_barrier();
  MEMFENCE;

  for (int t = 0; t < NT; ++t) {
    const int bb = t & 1;
#pragma unroll
    for (int mt = 0; mt < 4; ++mt) { af[mt][0] = ldA(bb, mt, 0); af[mt][1] = ldA(bb, mt, 1); }
#pragma unroll
    for (int nt = 0; nt < 2; ++nt) { bfr[nt][0] = ldB(bb, nt, 0); bfr[nt][1] = ldB(bb, nt, 1); }
    if (t + 1 < NT) stageB(t + 1, 0);
    MEMFENCE; __builtin_amdgcn_s_barrier(); MEMFENCE;
    __builtin_amdgcn_s_setprio(1);
#pragma unroll
    for (int mt = 0; mt < 4; ++mt)
#pragma unroll
      for (int nt = 0; nt < 2; ++nt)
#pragma unroll
        for (int ks = 0; ks < 2; ++ks) acc[mt][nt] = MFMA16(af[mt][ks], bfr[nt][ks], acc[mt][nt]);
    __builtin_amdgcn_s_setprio(0);
    MEMFENCE; __builtin_amdgcn_s_barrier(); MEMFENCE;
    bfr[2][0] = ldB(bb, 2, 0); bfr[2][1] = ldB(bb, 2, 1);
    if (t + 1 < NT) { stageB(t + 1, 1); stageB(t + 1, 2); }
    if (t + 2 < NT) stageA(t + 2);
    MEMFENCE; __builtin_amdgcn_s_barrier(); MEMFENCE;
    __builtin_amdgcn_s_setprio(1);
#pragma unroll
    for (int mt = 0; mt < 4; ++mt)
#pragma unroll
      for (int ks = 0; ks < 2; ++ks) acc[mt][2] = MFMA16(af[mt][ks], bfr[2][ks], acc[mt][2]);
    __builtin_amdgcn_s_setprio(0);
    if (t + 2 < NT) {
      asm volatile("s_waitcnt vmcnt(2)" ::: "memory");
    } else {
      asm volatile("s_waitcnt vmcnt(0)" ::: "memory");
    }
    __builtin_amdgcn_s_barrier();
    MEMFENCE;
  }

#pragma unroll
  for (int mt = 0; mt < 4; ++mt) {
    int mrow = m0 + wr * 64 + mt * 16 + g4 * 4;
#pragma unroll
    for (int nt = 0; nt < 3; ++nt) {
      int e = wc * 48 + nt * 16 + lo;
      float bv = bias[bx * 192 + e];
#pragma unroll
      for (int r = 0; r < 4; ++r) {
        int mm = mrow + r;
        int b = mm >> 11, n = mm & 2047;
        float v = acc[mt][nt][r] + bv;
        size_t bh64 = (size_t)(b * 16 + bx);
        if (e < 64)       Kout[(bh64 * 2048 + n) * 64 + e] = __float2bfloat16(v);
        else if (e < 128) Qout[(bh64 * 2048 + n) * 64 + e - 64] = __float2bfloat16(v * QSCALE);
        else              Vtout[(bh64 * 64 + (e - 128)) * 2048 + n] = __float2bfloat16(v);
      }
    }
  }
}

// ---------------- proj GEMM v2: 64x128x64 tiles -> 512 blocks (3/CU capable), counted vmcnt ----------------
// C[4096,1024] = Ob * wproj_t^T + bias (fp32 out). 256 thr = 4 waves (2M x 2N), wave C = 32x64.
// LDS 48KB (A 2x8KB, B 2x16KB). 6 load-units/tile; steady vmcnt(2) = next-next A in flight.
__launch_bounds__(256, 3)
__global__ void gemm_proj_k(const HBF* __restrict__ A, const HBF* __restrict__ Bt,
                            const float* __restrict__ bias, float* __restrict__ Cout) {
  __shared__ __align__(16) HBF As[2][4096];   // 64 x 64
  __shared__ __align__(16) HBF Bs[2][8192];   // 128 x 64
  const int tid = threadIdx.x, lane = tid & 63, w = tid >> 6;
  const int lo = lane & 15, g4 = lane >> 4;
  const int wrp = w >> 1, wcp = w & 1;
  // XCD-aware bijective swizzle: 512 = 8 * 64
  const int s = ((int)blockIdx.x & 7) * 64 + ((int)blockIdx.x >> 3);
  const int bxn = s & 7, by = s >> 3;
  const int m0 = by * 64, n0 = bxn * 128;
  const int NT = 16;  // K=1024 / 64

  f32x4 acc[2][4];
#pragma unroll
  for (int i = 0; i < 2; i++)
#pragma unroll
    for (int j = 0; j < 4; j++) acc[i][j] = (f32x4){0.f, 0.f, 0.f, 0.f};
  bf16x8 af[2][2], bfr[4][2];

  const int rr = tid >> 3;   // 0..31 (row within 32-row unit)
  const int ch = tid & 7;    // 16B chunk in row

  // A 32-row half h of K-tile kt: 1 load/thread
  auto stageA = [&](int kt, int h) {
    int row = h * 32 + rr;
    gload_lds16(A + (size_t)(m0 + row) * 1024 + kt * 64 + ((ch ^ (row & 7)) * 8),
                &As[kt & 1][h * 2048] + w * 512);
  };
  // B 32-row quarter g of K-tile kt: 1 load/thread
  auto stageB = [&](int kt, int g) {
    int row = g * 32 + rr;
    gload_lds16(Bt + (size_t)(n0 + row) * 1024 + kt * 64 + ((ch ^ (row & 7)) * 8),
                &Bs[kt & 1][g * 2048] + w * 512);
  };
  auto ldA = [&](int bb, int mt, int ks) -> bf16x8 {
    int row = wrp * 32 + mt * 16 + lo;
    return *reinterpret_cast<const bf16x8*>(&As[bb][row * 64 + ((ks * 32 + g4 * 8) ^ ((row & 7) * 8))]);
  };
  auto ldB = [&](int bb, int nt, int ks) -> bf16x8 {
    int row = wcp * 64 + nt * 16 + lo;
    return *reinterpret_cast<const bf16x8*>(&Bs[bb][row * 64 + ((ks * 32 + g4 * 8) ^ ((row & 7) * 8))]);
  };

  // prologue: tile0 (A 2 + B 4 = 6) + tile1 A (2); vmcnt(2) -> tile0 complete
  stageA(0, 0); stageA(0, 1);
  stageB(0, 0); stageB(0, 1); stageB(0, 2); stageB(0, 3);
  stageA(1, 0); stageA(1, 1);
  asm volatile("s_waitcnt vmcnt(2)" ::: "memory");
  __builtin_amdgcn_s_barrier();
  MEMFENCE;

  for (int t = 0; t < NT; ++t) {
    const int bb = t & 1;
    // ---- P0: read A + B nt0-1; stage B(t+1) 0,1; MFMA x nt0-1 ----
#pragma unroll
    for (int mt = 0; mt < 2; ++mt) { af[mt][0] = ldA(bb, mt, 0); af[mt][1] = ldA(bb, mt, 1); }
#pragma unroll
    for (int nt = 0; nt < 2; ++nt) { bfr[nt][0] = ldB(bb, nt, 0); bfr[nt][1] = ldB(bb, nt, 1); }
    if (t + 1 < NT) { stageB(t + 1, 0); stageB(t + 1, 1); }
    MEMFENCE; __builtin_amdgcn_s_barrier(); MEMFENCE;
    __builtin_amdgcn_s_setprio(1);
#pragma unroll
    for (int mt = 0; mt < 2; ++mt)
#pragma unroll
      for (int nt = 0; nt < 2; ++nt)
#pragma unroll
        for (int ks = 0; ks < 2; ++ks) acc[mt][nt] = MFMA16(af[mt][ks], bfr[nt][ks], acc[mt][nt]);
    __builtin_amdgcn_s_setprio(0);
    MEMFENCE; __builtin_amdgcn_s_barrier(); MEMFENCE;
    // ---- P1: read B nt2-3; stage B(t+1) 2,3 + A(t+2); MFMA x nt2-3; counted wait ----
#pragma unroll
    for (int nt = 2; nt < 4; ++nt) { bfr[nt][0] = ldB(bb, nt, 0); bfr[nt][1] = ldB(bb, nt, 1); }
    if (t + 1 < NT) { stageB(t + 1, 2); stageB(t + 1, 3); }
    if (t + 2 < NT) { stageA(t + 2, 0); stageA(t + 2, 1); }
    MEMFENCE; __builtin_amdgcn_s_barrier(); MEMFENCE;
    __builtin_amdgcn_s_setprio(1);
#pragma unroll
    for (int mt = 0; mt < 2; ++mt)
#pragma unroll
      for (int nt = 2; nt < 4; ++nt)
#pragma unroll
        for (int ks = 0; ks < 2; ++ks) acc[mt][nt] = MFMA16(af[mt][ks], bfr[nt][ks], acc[mt][nt]);
    __builtin_amdgcn_s_setprio(0);
    if (t + 2 < NT) {
      asm volatile("s_waitcnt vmcnt(2)" ::: "memory");  // leave A(t+2) in flight
    } else {
      asm volatile("s_waitcnt vmcnt(0)" ::: "memory");  // tail drain
    }
    __builtin_amdgcn_s_barrier();
    MEMFENCE;
  }

  // ---- epilogue: fp32 + bias ----
#pragma unroll
  for (int mt = 0; mt < 2; ++mt) {
    int mrow = m0 + wrp * 32 + mt * 16 + g4 * 4;
#pragma unroll
    for (int nt = 0; nt < 4; ++nt) {
      int col = n0 + wcp * 64 + nt * 16 + lo;
      float bv = bias[col];
#pragma unroll
      for (int r = 0; r < 4; ++r)
        Cout[(size_t)(mrow + r) * 1024 + col] = acc[mt][nt][r] + bv;
    }
  }
}

// ---------------- causal flash attention v9: v7 skeleton, KVBLK=128 ----------------
__launch_bounds__(256, 2)
__global__ void attn_fwd_k(const HBF* __restrict__ Qb, const HBF* __restrict__ Kb,
                           const HBF* __restrict__ Vt, HBF* __restrict__ Ob) {
  __shared__ __align__(16) HBF Ks[2][2][4096];  // [dbuf][sub][64key x 64d]
  __shared__ __align__(16) HBF Vs[2][2][4096];  // [dbuf][sub][64d x 64key]
  __shared__ __align__(16) HBF pLds[4][2048];   // wave-local 16 q x 128 key
  const int tid = threadIdx.x;
  const int lane = tid & 63;
  const int w = tid >> 6;
  const int lo = lane & 15, g4 = lane >> 4;

  const int lin = blockIdx.x;
  const int xcd = lin & 7, c = lin >> 3;       // c in 0..127
  const int bh = xcd * 4 + (c & 3);            // 4 (b,h) per XCD -> KV L2-clustered
  const int j = 31 - (c >> 2);                 // longest tiles dispatched first
  const int b = bh >> 4, h = bh & 15;
  const int qrow0 = j * 64 + w * 16;
  const int nkv = (j + 2) >> 1;                // 128-key iterations

  const HBF* Qp = Qb + (size_t)bh * 2048 * 64;
  const HBF* Kp = Kb + (size_t)bh * 2048 * 64;
  const HBF* Vp = Vt + (size_t)bh * 64 * 2048;

  bf16x8 qf[2];
#pragma unroll
  for (int ds = 0; ds < 2; ds++)
    qf[ds] = *reinterpret_cast<const bf16x8*>(Qp + (size_t)(qrow0 + lo) * 64 + ds * 32 + g4 * 8);

  const f32x4 zero = {0.f, 0.f, 0.f, 0.f};
  f32x4 o[4];
  float m = -1e30f, l = 0.f;
#pragma unroll
  for (int j4 = 0; j4 < 4; j4++) o[j4] = zero;

  const int srow = (lane >> 3) & 7;
  const int sch = lane & 7;
  const int psw = (lo & 7) << 4;  // pLds XOR key (bytes)

  auto stage = [&](int kv0, int sb) {  // kv0 = 128-aligned
#pragma unroll
    for (int sub = 0; sub < 2; sub++)
#pragma unroll
      for (int cc = 0; cc < 2; cc++) {
        int seg = w * 2 + cc;
        int row = seg * 8 + srow;
        gload_lds16(Kp + (size_t)(kv0 + sub * 64 + row) * 64 + ((sch ^ (row & 7)) * 8),
                    &Ks[sb][sub][seg * 512]);
        gload_lds16(Vp + (size_t)row * 2048 + kv0 + sub * 64 + ((sch ^ (row & 7)) * 8),
                    &Vs[sb][sub][seg * 512]);
      }
  };

  stage(0, 0);
  __syncthreads();

  for (int t = 0; t < nkv; ++t) {
    const int kv0 = t * 128;
    const int sb = t & 1;
    if (t + 1 < nkv) stage(kv0 + 128, sb ^ 1);  // prefetch under compute

    // ---- S^T = K · Q^T over 128 keys (2 subs x 4 kt) ----
    f32x4 st[2][4];
#pragma unroll
    for (int sub = 0; sub < 2; sub++)
#pragma unroll
      for (int kt = 0; kt < 4; kt++) {
        int krow = kt * 16 + lo;
        bf16x8 kf0 = *reinterpret_cast<const bf16x8*>(&Ks[sb][sub][krow * 64 + ((g4 ^ (krow & 7)) * 8)]);
        bf16x8 kf1 = *reinterpret_cast<const bf16x8*>(&Ks[sb][sub][krow * 64 + (((4 + g4) ^ (krow & 7)) * 8)]);
        f32x4 z = zero;
        z = MFMA16(kf0, qf[0], z);
        z = MFMA16(kf1, qf[1], z);
        st[sub][kt] = z;
      }

    // ---- online softmax (lane owns q-col = qrow0 + lo) ----
    const int q = qrow0 + lo;
    float pmax = -1e30f;
    if (t == nkv - 1) {  // diagonal iter: mask
#pragma unroll
      for (int sub = 0; sub < 2; sub++)
#pragma unroll
        for (int kt = 0; kt < 4; kt++)
#pragma unroll
          for (int r = 0; r < 4; r++) {
            int key = kv0 + sub * 64 + kt * 16 + g4 * 4 + r;
            float v = (key <= q) ? st[sub][kt][r] : -1e30f;
            st[sub][kt][r] = v;
            pmax = fmaxf(pmax, v);
          }
    } else {
#pragma unroll
      for (int sub = 0; sub < 2; sub++)
#pragma unroll
        for (int kt = 0; kt < 4; kt++)
#pragma unroll
          for (int r = 0; r < 4; r++) pmax = fmaxf(pmax, st[sub][kt][r]);
    }
    pmax = fmaxf(pmax, __shfl_xor(pmax, 16));
    pmax = fmaxf(pmax, __shfl_xor(pmax, 32));
    if (__any(pmax > m + 11.5f)) {  // defer-max
      float mn = fmaxf(m, pmax);
      float al = EXP2F(m - mn);
      m = mn;
      l *= al;
      float alr[4];
#pragma unroll
      for (int r = 0; r < 4; r++) alr[r] = __shfl(al, g4 * 4 + r);
#pragma unroll
      for (int j4 = 0; j4 < 4; j4++)
#pragma unroll
        for (int r = 0; r < 4; r++) o[j4][r] *= alr[r];
    }
#pragma unroll
    for (int sub = 0; sub < 2; sub++)
#pragma unroll
      for (int kt = 0; kt < 4; kt++)
#pragma unroll
        for (int r = 0; r < 4; r++) {
          float p = EXP2F(st[sub][kt][r] - m);
          st[sub][kt][r] = p;
          l += p;  // lane-partial; reduced in epilogue
        }
    // pack P -> swizzled pLds
#pragma unroll
    for (int sub = 0; sub < 2; sub++)
#pragma unroll
      for (int kt = 0; kt < 4; kt++) {
        bf16x4 pk;
#pragma unroll
        for (int r = 0; r < 4; r++) pk[r] = (__bf16)st[sub][kt][r];
        *reinterpret_cast<bf16x4*>(
            &pLds[w][lo * 128 + (((sub * 128 + kt * 32 + g4 * 8) ^ psw) >> 1)]) = pk;
      }
    asm volatile("s_waitcnt lgkmcnt(0)" ::: "memory");
    __builtin_amdgcn_sched_barrier(0);

    // ---- PV: 4 ks-groups of 32 keys ----
    bf16x8 pa[4];
#pragma unroll
    for (int ks = 0; ks < 4; ks++)
      pa[ks] = *reinterpret_cast<const bf16x8*>(
          &pLds[w][lo * 128 + (((ks * 64 + g4 * 16) ^ psw) >> 1)]);
#pragma unroll
    for (int j4 = 0; j4 < 4; j4++) {
      int vrow = j4 * 16 + lo;
#pragma unroll
      for (int ks = 0; ks < 4; ks++) {
        bf16x8 vb = *reinterpret_cast<const bf16x8*>(
            &Vs[sb][ks >> 1][vrow * 64 + ((((ks & 1) * 4 + g4) ^ (vrow & 7)) * 8)]);
        o[j4] = MFMA16(pa[ks], vb, o[j4]);
      }
    }
    __syncthreads();  // drains prefetch + protects LDS reuse
  }

  // ---- epilogue ----
  l += __shfl_xor(l, 16);
  l += __shfl_xor(l, 32);
  float linv = 1.f / l;
  float lr[4];
#pragma unroll
  for (int r = 0; r < 4; r++) lr[r] = __shfl(linv, g4 * 4 + r);
#pragma unroll
  for (int j4 = 0; j4 < 4; j4++)
#pragma unroll
    for (int r = 0; r < 4; r++) {
      int q = qrow0 + g4 * 4 + r;
      Ob[(size_t)(b * 2048 + q) * 1024 + h * 64 + j4 * 16 + lo] =
          __float2bfloat16(o[j4][r] * lr[r]);
    }
}

// ---------------- launch ----------------
extern "C" void kernel_launch(void* const* d_in, const int* in_sizes, int n_in,
                              void* d_out, int out_size, void* d_ws, size_t ws_size,
                              hipStream_t stream) {
  const float* x      = (const float*)d_in[0];
  const float* W_qkv  = (const float*)d_in[1];
  const float* b_qkv  = (const float*)d_in[2];
  const float* W_proj = (const float*)d_in[3];
  const float* b_proj = (const float*)d_in[4];
  float* out = (float*)d_out;

  const int B = 2, N = 2048, D = 1024, H = 16, DH = 64;
  const int M = B * N;  // 4096

  char* ws = (char*)d_ws;
  HBF* xb      = (HBF*)ws; ws += (size_t)M * D * 2;
  HBF* wqkv_t  = (HBF*)ws; ws += (size_t)H * 3 * DH * D * 2;
  HBF* wproj_t = (HBF*)ws; ws += (size_t)D * D * 2;
  HBF* Qb      = (HBF*)ws; ws += (size_t)B * H * N * DH * 2;
  HBF* Kb      = (HBF*)ws; ws += (size_t)B * H * N * DH * 2;
  HBF* Vt      = (HBF*)ws; ws += (size_t)B * H * DH * N * 2;
  HBF* Ob      = (HBF*)ws; ws += (size_t)M * D * 2;

  prep_k<<<8192, 256, 0, stream>>>(x, xb, W_qkv, wqkv_t, W_proj, wproj_t);
  gemm_qkv_8ph<<<512, 512, 0, stream>>>(xb, wqkv_t, b_qkv, Kb, Qb, Vt);
  attn_fwd_k<<<1024, 256, 0, stream>>>(Qb, Kb, Vt, Ob);
  gemm_proj_k<<<512, 256, 0, stream>>>(Ob, wproj_t, b_proj, out);
}